// Round 4
// baseline (1509.803 us; speedup 1.0000x reference)
//
#include <hip/hip_runtime.h>

#define LNEPS 1e-5f

typedef unsigned short ushort_t;
typedef __attribute__((ext_vector_type(8))) short short8;   // bf16x8 MFMA frag
typedef __attribute__((ext_vector_type(4))) float f32x4;    // fp32x4 accum frag

__device__ inline unsigned short f2b(float f) {
    union { float f; unsigned int u; } c; c.f = f;
    unsigned int u = c.u;
    unsigned int r = (u + 0x7FFFu + ((u >> 16) & 1u)) >> 16;  // RNE
    return (unsigned short)r;
}

// ---------------------------------------------------------------------------
// Weight packing into MFMA B-fragment order (wave-contiguous 1KB loads).
// w1P: [L][c=32][kb=8][lane][8]; K=256 = [ed 0..127 | nd_j 0..127]
//      frag elem: col = c*16+(lane&15); kl = kb*32+(lane>>4)*8+e;
//      W1 row = kl<128 ? kl : kl+128   (skips the hoisted nd_i rows 128..255)
// w2P: [L][c2=8][kbg=16][lane][8]; k order = staged-h permutation:
//      k_staged = kbg*32+(lane>>4)*8+e; half=k>>8; p=k&255;
//      W2 row = (p>>6)*128 + half*64 + (p&63)
// ---------------------------------------------------------------------------
__global__ void k_convw(const float* __restrict__ w1, const float* __restrict__ w2,
                        ushort_t* __restrict__ w1P, ushort_t* __restrict__ w2P) {
    int idx = blockIdx.x * 256 + threadIdx.x;   // chunk index (8 elems each)
    if (idx < 65536) {
        int l = idx >> 14, r = idx & 16383;
        int c = r >> 9;  r &= 511;
        int kb = r >> 6, lane = r & 63;
        int col = c * 16 + (lane & 15);
        int k0 = kb * 32 + (lane >> 4) * 8;
        ushort_t o[8];
        #pragma unroll
        for (int e = 0; e < 8; ++e) {
            int kl = k0 + e;
            int row = kl < 128 ? kl : kl + 128;
            o[e] = f2b(w1[((size_t)l * 384 + row) * 512 + col]);
        }
        *(uint4*)(w1P + (size_t)idx * 8) = *(uint4*)o;
    }
    if (idx < 32768) {
        int l = idx >> 13, r = idx & 8191;
        int c2 = r >> 10; r &= 1023;
        int kbg = r >> 6, lane = r & 63;
        int col = c2 * 16 + (lane & 15);
        int k0 = kbg * 32 + (lane >> 4) * 8;
        ushort_t o[8];
        #pragma unroll
        for (int e = 0; e < 8; ++e) {
            int ks = k0 + e;
            int half = ks >> 8, p = ks & 255;
            int row = (p >> 6) * 128 + half * 64 + (p & 63);
            o[e] = f2b(w2[((size_t)l * 512 + row) * 128 + col]);
        }
        *(uint4*)(w2P + (size_t)idx * 8) = *(uint4*)o;
    }
}

// ---------------------------------------------------------------------------
// Edge init: dist, adj, edges = relu(LN(dist*ee_w + ee_b))   one wave per row
// ---------------------------------------------------------------------------
__global__ void k_init(const float* __restrict__ coords,
                       const float* __restrict__ ee_w, const float* __restrict__ ee_b,
                       const float* __restrict__ ee_g, const float* __restrict__ ee_bt,
                       float* __restrict__ ed, float* __restrict__ adjf) {
    int r = blockIdx.x * 4 + (threadIdx.x >> 6);
    int lane = threadIdx.x & 63;
    int i = r >> 8, j = r & 255;
    float dx = coords[i * 3 + 0] - coords[j * 3 + 0];
    float dy = coords[i * 3 + 1] - coords[j * 3 + 1];
    float dz = coords[i * 3 + 2] - coords[j * 3 + 2];
    float sq = dx * dx + dy * dy + dz * dz;
    float dist = sq > 0.f ? sqrtf(sq) : 0.f;
    if (lane == 0) adjf[r] = dist < 10.f ? 1.f : 0.f;
    float e0 = dist * ee_w[lane] + ee_b[lane];
    float e1 = dist * ee_w[lane + 64] + ee_b[lane + 64];
    float s = e0 + e1, q = e0 * e0 + e1 * e1;
    #pragma unroll
    for (int off = 1; off < 64; off <<= 1) {
        s += __shfl_xor(s, off, 64);
        q += __shfl_xor(q, off, 64);
    }
    float mean = s * (1.f / 128.f);
    float var = q * (1.f / 128.f) - mean * mean;
    float rs = rsqrtf(var + LNEPS);
    ed[(size_t)r * 128 + lane]      = fmaxf((e0 - mean) * rs * ee_g[lane] + ee_bt[lane], 0.f);
    ed[(size_t)r * 128 + lane + 64] = fmaxf((e1 - mean) * rs * ee_g[lane + 64] + ee_bt[lane + 64], 0.f);
}

// ---------------------------------------------------------------------------
// Per-layer node precompute (fp32):
//   cI[p][t] = b1[t] + sum_k nd[p][k] * W1[(128+k)][t]
// also ndb[p][*] = bf16(nd[p][*]).   one block per node p, 512 threads.
// ---------------------------------------------------------------------------
__global__ __launch_bounds__(512) void k_pre(
    const float* __restrict__ nd, const float* __restrict__ W1,
    const float* __restrict__ b1,
    float* __restrict__ cI, ushort_t* __restrict__ ndb) {
    __shared__ float ndl[128];
    int p = blockIdx.x, t = threadIdx.x;
    if (t < 128) {
        float v = nd[(size_t)p * 128 + t];
        ndl[t] = v;
        ndb[(size_t)p * 128 + t] = f2b(v);
    }
    __syncthreads();
    const float* wm = W1 + (size_t)128 * 512 + t;
    float a1 = b1[t];
    #pragma unroll 4
    for (int k = 0; k < 128; ++k) a1 += ndl[k] * wm[(size_t)k * 512];
    cI[(size_t)p * 512 + t] = a1;
}

// ---------------------------------------------------------------------------
// msgs[r] = adj[r] * dot(ed[r][:], nd[i][:])   one wave per row
// ---------------------------------------------------------------------------
__global__ void k_msgs(const float* __restrict__ ed, const float* __restrict__ nd,
                       const float* __restrict__ adjf, float* __restrict__ msgs) {
    int r = blockIdx.x * 4 + (threadIdx.x >> 6);
    int lane = threadIdx.x & 63;
    int i = r >> 8;
    const float* er = ed + (size_t)r * 128;
    const float* nr = nd + (size_t)i * 128;
    float sum = er[lane] * nr[lane] + er[lane + 64] * nr[lane + 64];
    #pragma unroll
    for (int off = 1; off < 64; off <<= 1) sum += __shfl_xor(sum, off, 64);
    if (lane == 0) msgs[r] = adjf[r] * sum;
}

// ---------------------------------------------------------------------------
// Generic fp32 row-MLP: out = [res +] relu(LN(concat(in0,in1) @ W1 + b1)) @ W2 + b2
// one block (512 threads) per row; K = w0 + w1n <= 384; O <= 128
// ---------------------------------------------------------------------------
__global__ __launch_bounds__(512) void k_mlp(
    const float* __restrict__ in0, int w0, const float* __restrict__ in1, int w1n,
    const float* __restrict__ W1, const float* __restrict__ b1,
    const float* __restrict__ g, const float* __restrict__ bt,
    const float* __restrict__ W2, const float* __restrict__ b2, int O,
    const float* __restrict__ res, float* __restrict__ out) {
    __shared__ float ni[384];
    __shared__ float hsh[512];
    __shared__ float part[4][128];
    __shared__ float red[16];
    int row = blockIdx.x;
    int t = threadIdx.x;
    int K = w0 + w1n;
    if (t < w0) ni[t] = in0[(size_t)row * w0 + t];
    else if (t < K) ni[t] = in1[(size_t)row * w1n + (t - w0)];
    __syncthreads();
    float acc = b1[t];
    #pragma unroll 4
    for (int k = 0; k < K; ++k) acc += ni[k] * W1[(size_t)k * 512 + t];
    float s = acc, q = acc * acc;
    #pragma unroll
    for (int off = 1; off < 64; off <<= 1) {
        s += __shfl_xor(s, off, 64);
        q += __shfl_xor(q, off, 64);
    }
    int wv = t >> 6;
    if ((t & 63) == 0) { red[wv] = s; red[8 + wv] = q; }
    __syncthreads();
    float S = 0.f, Q = 0.f;
    #pragma unroll
    for (int w = 0; w < 8; ++w) { S += red[w]; Q += red[8 + w]; }
    float mean = S * (1.f / 512.f);
    float var = Q * (1.f / 512.f) - mean * mean;
    float rs = rsqrtf(var + LNEPS);
    hsh[t] = fmaxf((acc - mean) * rs * g[t] + bt[t], 0.f);
    __syncthreads();
    int qd = t >> 7, c = t & 127;
    float pacc = 0.f;
    if (c < O) {
        #pragma unroll 4
        for (int kk = 0; kk < 128; ++kk)
            pacc += hsh[qd * 128 + kk] * W2[(size_t)(qd * 128 + kk) * O + c];
    }
    part[qd][c] = pacc;
    __syncthreads();
    if (t < O) {
        float v = part[0][t] + part[1][t] + part[2][t] + part[3][t] + b2[t];
        if (res) v += res[(size_t)row * O + t];
        out[(size_t)row * O + t] = v;
    }
}

// ---------------------------------------------------------------------------
// Fused edge update (in-place on ed), bf16 MFMA, K=256 (nd_i hoisted to cI).
// Block: 256 threads (4 waves), 64 edge rows; i fixed, j = jbase + row.
//   h_pre = [ed_row | nd_j] @ W1' (MFMA) + cI[i]  -> LN -> relu
//   out   = h @ W2 + b2 + ed_row  (in-place)
// LDS 35.3KB: stage ei [64 rows][32 ch][16B] swz @0 (32KB)
//             h-half [64 rows][32 ch][16B] swz @0 (reuses stage; K-split halves)
//             red [4][64][2] f32 @32768, stats [64][2] f32 @34816
// GEMM2: wave w owns rows w*16..w*16+15, all 128 cols; acc2 carried over halves.
// ---------------------------------------------------------------------------
__global__ __launch_bounds__(256, 4) void k_edge(
    float* ed, const ushort_t* __restrict__ ndb, const float* __restrict__ cIg,
    const ushort_t* __restrict__ w1P,
    const float* __restrict__ g, const float* __restrict__ bt,
    const ushort_t* __restrict__ w2P, const float* __restrict__ b2) {
    __shared__ char smem[35328];
    const int tid = threadIdx.x;
    const int w = tid >> 6, lane = tid & 63;
    const int l15 = lane & 15, lhi = lane >> 4;
    const int rbase = blockIdx.x * 64;
    const int ib = rbase >> 8;          // fixed node i for this block
    const int jbase = rbase & 255;

    // ---- stage ei = [ed bf16 | ndb] : 64 rows x 32 chunks(16B), XOR-swz by row&7
    #pragma unroll
    for (int it = 0; it < 8; ++it) {
        int c = tid + it * 256;
        int row = c >> 5, q = c & 31;
        uint4 pk;
        if (q < 16) {
            const float4* sp = (const float4*)(ed + (size_t)(rbase + row) * 128 + q * 8);
            float4 v0 = sp[0], v1 = sp[1];
            pk.x = (unsigned)f2b(v0.x) | ((unsigned)f2b(v0.y) << 16);
            pk.y = (unsigned)f2b(v0.z) | ((unsigned)f2b(v0.w) << 16);
            pk.z = (unsigned)f2b(v1.x) | ((unsigned)f2b(v1.y) << 16);
            pk.w = (unsigned)f2b(v1.z) | ((unsigned)f2b(v1.w) << 16);
        } else {
            pk = *(const uint4*)(ndb + (size_t)(jbase + row) * 128 + (q - 16) * 8);
        }
        *(uint4*)(smem + row * 512 + ((q ^ (row & 7)) * 16)) = pk;
    }
    __syncthreads();

    // ---- GEMM1: wave w -> hidden cols [w*128, w*128+128), K=256 (8 kb)
    f32x4 acc[4][8];
    f32x4 zero = {0.f, 0.f, 0.f, 0.f};
    #pragma unroll
    for (int m = 0; m < 4; ++m)
        #pragma unroll
        for (int n = 0; n < 8; ++n) acc[m][n] = zero;

    const int cw = w * 128;
    #pragma unroll 2
    for (int kb = 0; kb < 8; ++kb) {
        short8 a[4];
        #pragma unroll
        for (int m = 0; m < 4; ++m) {
            int row = m * 16 + l15;
            a[m] = *(const short8*)(smem + row * 512 + (((kb * 4 + lhi) ^ (row & 7)) * 16));
        }
        #pragma unroll
        for (int n = 0; n < 8; ++n) {
            short8 b = *(const short8*)(w1P + ((((w * 8 + n) * 8 + kb) << 6) + lane) * 8);
            #pragma unroll
            for (int m = 0; m < 4; ++m)
                acc[m][n] = __builtin_amdgcn_mfma_f32_16x16x32_bf16(a[m], b, acc[m][n], 0, 0, 0);
        }
    }

    // ---- add cI (broadcast, i fixed), LN stats per row
    float* red = (float*)(smem + 32768);     // [4][64][2]
    float* stats = (float*)(smem + 34816);   // [64][2]
    {
        float ci[8];
        #pragma unroll
        for (int n = 0; n < 8; ++n) ci[n] = cIg[(size_t)ib * 512 + cw + n * 16 + l15];
        #pragma unroll
        for (int m = 0; m < 4; ++m) {
            float s[4] = {0.f, 0.f, 0.f, 0.f}, q[4] = {0.f, 0.f, 0.f, 0.f};
            #pragma unroll
            for (int n = 0; n < 8; ++n)
                #pragma unroll
                for (int e = 0; e < 4; ++e) {
                    float v = acc[m][n][e] + ci[n];
                    acc[m][n][e] = v;
                    s[e] += v; q[e] += v * v;
                }
            #pragma unroll
            for (int off = 1; off < 16; off <<= 1)
                #pragma unroll
                for (int e = 0; e < 4; ++e) {
                    s[e] += __shfl_xor(s[e], off, 64);
                    q[e] += __shfl_xor(q[e], off, 64);
                }
            if (l15 == 0) {
                #pragma unroll
                for (int e = 0; e < 4; ++e) {
                    int row = m * 16 + lhi * 4 + e;
                    red[(w * 64 + row) * 2 + 0] = s[e];
                    red[(w * 64 + row) * 2 + 1] = q[e];
                }
            }
        }
    }
    __syncthreads();
    if (tid < 64) {
        float S = 0.f, Q = 0.f;
        #pragma unroll
        for (int ww = 0; ww < 4; ++ww) {
            S += red[(ww * 64 + tid) * 2 + 0];
            Q += red[(ww * 64 + tid) * 2 + 1];
        }
        float mean = S * (1.f / 512.f);
        float var = Q * (1.f / 512.f) - mean * mean;
        stats[tid * 2 + 0] = mean;
        stats[tid * 2 + 1] = rsqrtf(var + LNEPS);
    }
    __syncthreads();
    {
        float gg[8], bb[8];
        #pragma unroll
        for (int n = 0; n < 8; ++n) {
            gg[n] = g[cw + n * 16 + l15];
            bb[n] = bt[cw + n * 16 + l15];
        }
        #pragma unroll
        for (int m = 0; m < 4; ++m)
            #pragma unroll
            for (int e = 0; e < 4; ++e) {
                int row = m * 16 + lhi * 4 + e;
                float mean = stats[row * 2 + 0];
                float rs = stats[row * 2 + 1];
                #pragma unroll
                for (int n = 0; n < 8; ++n)
                    acc[m][n][e] = fmaxf((acc[m][n][e] - mean) * rs * gg[n] + bb[n], 0.f);
            }
    }

    // ---- GEMM2, K-split over two h-halves; wave w -> rows w*16..w*16+15, 128 cols
    // staged-h layout per half: p = wsrc*64 + n4*16 + l15, ch = p>>3, swz by row&7
    f32x4 acc2[8];
    #pragma unroll
    for (int c2 = 0; c2 < 8; ++c2) acc2[c2] = zero;

    #pragma unroll
    for (int hf = 0; hf < 2; ++hf) {
        __syncthreads();   // prev reads of smem region done (stage / GEMM2-half0)
        #pragma unroll
        for (int n4 = 0; n4 < 4; ++n4) {
            int n = hf * 4 + n4;
            int p = w * 64 + n4 * 16 + l15;
            #pragma unroll
            for (int m = 0; m < 4; ++m)
                #pragma unroll
                for (int e = 0; e < 4; ++e) {
                    int row = m * 16 + lhi * 4 + e;
                    int addr = row * 512 + (((p >> 3) ^ (row & 7)) * 16) + (p & 7) * 2;
                    *(ushort_t*)(smem + addr) = f2b(acc[m][n][e]);
                }
        }
        __syncthreads();
        int arow = w * 16 + l15;
        #pragma unroll 2
        for (int kb = 0; kb < 8; ++kb) {
            short8 a = *(const short8*)(smem + arow * 512 + (((kb * 4 + lhi) ^ (arow & 7)) * 16));
            #pragma unroll
            for (int c2 = 0; c2 < 8; ++c2) {
                short8 b = *(const short8*)(w2P + ((((c2 * 16) + hf * 8 + kb) << 6) + lane) * 8);
                acc2[c2] = __builtin_amdgcn_mfma_f32_16x16x32_bf16(a, b, acc2[c2], 0, 0, 0);
            }
        }
    }

    // ---- epilogue: residual + bias; wave writes full 512B rows
    #pragma unroll
    for (int c2 = 0; c2 < 8; ++c2) {
        int col = c2 * 16 + l15;
        float bc = b2[col];
        #pragma unroll
        for (int e = 0; e < 4; ++e) {
            int row = w * 16 + lhi * 4 + e;
            size_t off = (size_t)(rbase + row) * 128 + col;
            ed[off] = acc2[c2][e] + bc + ed[off];
        }
    }
}

// ---------------------------------------------------------------------------
extern "C" void kernel_launch(void* const* d_in, const int* in_sizes, int n_in,
                              void* d_out, int out_size, void* d_ws, size_t ws_size,
                              hipStream_t stream) {
    const float* nodes  = (const float*)d_in[0];
    const float* coords = (const float*)d_in[1];
    const float* ee_w   = (const float*)d_in[2];
    const float* ee_b   = (const float*)d_in[3];
    const float* ee_g   = (const float*)d_in[4];
    const float* ee_bt  = (const float*)d_in[5];
    const float* nu1_w  = (const float*)d_in[6];
    const float* nu1_b  = (const float*)d_in[7];
    const float* nu_g   = (const float*)d_in[8];
    const float* nu_bt  = (const float*)d_in[9];
    const float* nu2_w  = (const float*)d_in[10];
    const float* nu2_b  = (const float*)d_in[11];
    const float* eu1_w  = (const float*)d_in[12];
    const float* eu1_b  = (const float*)d_in[13];
    const float* eu_g   = (const float*)d_in[14];
    const float* eu_bt  = (const float*)d_in[15];
    const float* eu2_w  = (const float*)d_in[16];
    const float* eu2_b  = (const float*)d_in[17];
    const float* sp1_w  = (const float*)d_in[18];
    const float* sp1_b  = (const float*)d_in[19];
    const float* sp_g   = (const float*)d_in[20];
    const float* sp_bt  = (const float*)d_in[21];
    const float* sp2_w  = (const float*)d_in[22];
    const float* sp2_b  = (const float*)d_in[23];
    const float* no1_w  = (const float*)d_in[24];
    const float* no1_b  = (const float*)d_in[25];
    const float* no_g   = (const float*)d_in[26];
    const float* no_bt  = (const float*)d_in[27];
    const float* no2_w  = (const float*)d_in[28];
    const float* no2_b  = (const float*)d_in[29];

    char* p = (char*)d_ws;
    float* ed      = (float*)p;     p += (size_t)65536 * 128 * 4;   // 33.5 MB
    float* ndA     = (float*)p;     p += 256 * 128 * 4;
    float* ndB     = (float*)p;     p += 256 * 128 * 4;
    ushort_t* ndb  = (ushort_t*)p;  p += 256 * 128 * 2;
    float* msgs    = (float*)p;     p += 65536 * 4;
    float* adjf    = (float*)p;     p += 65536 * 4;
    float* cI      = (float*)p;     p += 256 * 512 * 4;
    ushort_t* w1P  = (ushort_t*)p;  p += (size_t)4 * 131072 * 2;    // 1 MB
    ushort_t* w2P  = (ushort_t*)p;  p += (size_t)4 * 65536 * 2;     // 512 KB

    k_convw<<<256, 256, 0, stream>>>(eu1_w, eu2_w, w1P, w2P);
    k_init<<<16384, 256, 0, stream>>>(coords, ee_w, ee_b, ee_g, ee_bt, ed, adjf);

    const float* nd_cur = nodes;
    float* nd_bufs[2] = {ndA, ndB};
    for (int l = 0; l < 4; ++l) {
        float* nd_next = nd_bufs[l & 1];
        k_pre<<<256, 512, 0, stream>>>(nd_cur, eu1_w + (size_t)l * 384 * 512,
                                       eu1_b + l * 512, cI, ndb);
        k_msgs<<<16384, 256, 0, stream>>>(ed, nd_cur, adjf, msgs);
        k_mlp<<<256, 512, 0, stream>>>(nd_cur, 128, msgs, 256,
            nu1_w + (size_t)l * 384 * 512, nu1_b + l * 512, nu_g + l * 512, nu_bt + l * 512,
            nu2_w + (size_t)l * 512 * 128, nu2_b + l * 128, 128, nd_cur, nd_next);
        k_edge<<<1024, 256, 0, stream>>>(ed, ndb, cI,
            w1P + (size_t)l * 131072, eu_g + l * 512, eu_bt + l * 512,
            w2P + (size_t)l * 65536, eu2_b + l * 128);
        nd_cur = nd_next;
    }

    float* out_nodes  = (float*)d_out;
    float* out_coords = out_nodes + 32768;
    k_mlp<<<256, 512, 0, stream>>>(nd_cur, 128, nullptr, 0,
        no1_w, no1_b, no_g, no_bt, no2_w, no2_b, 128, nullptr, out_nodes);
    k_mlp<<<256, 512, 0, stream>>>(out_nodes, 128, nullptr, 0,
        sp1_w, sp1_b, sp_g, sp_bt, sp2_w, sp2_b, 3, nullptr, out_coords);
}

// Round 5
// 625.580 us; speedup vs baseline: 2.4134x; 2.4134x over previous
//
#include <hip/hip_runtime.h>

#define LNEPS 1e-5f

typedef unsigned short ushort_t;
typedef __attribute__((ext_vector_type(8))) short short8;   // bf16x8 MFMA frag
typedef __attribute__((ext_vector_type(4))) float f32x4;    // fp32x4 accum frag

__device__ inline unsigned short f2b(float f) {
    union { float f; unsigned int u; } c; c.f = f;
    unsigned int u = c.u;
    unsigned int r = (u + 0x7FFFu + ((u >> 16) & 1u)) >> 16;  // RNE
    return (unsigned short)r;
}

// ---------------------------------------------------------------------------
// Weight packing into MFMA B-fragment order (wave-contiguous 1KB loads).
// w1P: [L][c=32][kb=8][lane][8]; K=256 = [ed 0..127 | nd_j 0..127]
//      frag elem: col = c*16+(lane&15); kl = kb*32+(lane>>4)*8+e;
//      W1 row = kl<128 ? kl : kl+128   (skips the hoisted nd_i rows 128..255)
// w2P: [L][c2=8][kbg=16][lane][8]; natural k-order:
//      W2 row = kbg*32+(lane>>4)*8+e; col = c2*16+(lane&15)
// ---------------------------------------------------------------------------
__global__ void k_convw(const float* __restrict__ w1, const float* __restrict__ w2,
                        ushort_t* __restrict__ w1P, ushort_t* __restrict__ w2P) {
    int idx = blockIdx.x * 256 + threadIdx.x;   // chunk index (8 elems each)
    if (idx < 65536) {
        int l = idx >> 14, r = idx & 16383;
        int c = r >> 9;  r &= 511;
        int kb = r >> 6, lane = r & 63;
        int col = c * 16 + (lane & 15);
        int k0 = kb * 32 + (lane >> 4) * 8;
        ushort_t o[8];
        #pragma unroll
        for (int e = 0; e < 8; ++e) {
            int kl = k0 + e;
            int row = kl < 128 ? kl : kl + 128;
            o[e] = f2b(w1[((size_t)l * 384 + row) * 512 + col]);
        }
        *(uint4*)(w1P + (size_t)idx * 8) = *(uint4*)o;
    }
    if (idx < 32768) {
        int l = idx >> 13, r = idx & 8191;
        int c2 = r >> 10; r &= 1023;
        int kbg = r >> 6, lane = r & 63;
        int col = c2 * 16 + (lane & 15);
        int k0 = kbg * 32 + (lane >> 4) * 8;
        ushort_t o[8];
        #pragma unroll
        for (int e = 0; e < 8; ++e)
            o[e] = f2b(w2[((size_t)l * 512 + k0 + e) * 128 + col]);
        *(uint4*)(w2P + (size_t)idx * 8) = *(uint4*)o;
    }
}

// ---------------------------------------------------------------------------
// Edge init: dist, adj, edges = relu(LN(dist*ee_w + ee_b))   one wave per row
// ---------------------------------------------------------------------------
__global__ void k_init(const float* __restrict__ coords,
                       const float* __restrict__ ee_w, const float* __restrict__ ee_b,
                       const float* __restrict__ ee_g, const float* __restrict__ ee_bt,
                       float* __restrict__ ed, float* __restrict__ adjf) {
    int r = blockIdx.x * 4 + (threadIdx.x >> 6);
    int lane = threadIdx.x & 63;
    int i = r >> 8, j = r & 255;
    float dx = coords[i * 3 + 0] - coords[j * 3 + 0];
    float dy = coords[i * 3 + 1] - coords[j * 3 + 1];
    float dz = coords[i * 3 + 2] - coords[j * 3 + 2];
    float sq = dx * dx + dy * dy + dz * dz;
    float dist = sq > 0.f ? sqrtf(sq) : 0.f;
    if (lane == 0) adjf[r] = dist < 10.f ? 1.f : 0.f;
    float e0 = dist * ee_w[lane] + ee_b[lane];
    float e1 = dist * ee_w[lane + 64] + ee_b[lane + 64];
    float s = e0 + e1, q = e0 * e0 + e1 * e1;
    #pragma unroll
    for (int off = 1; off < 64; off <<= 1) {
        s += __shfl_xor(s, off, 64);
        q += __shfl_xor(q, off, 64);
    }
    float mean = s * (1.f / 128.f);
    float var = q * (1.f / 128.f) - mean * mean;
    float rs = rsqrtf(var + LNEPS);
    ed[(size_t)r * 128 + lane]      = fmaxf((e0 - mean) * rs * ee_g[lane] + ee_bt[lane], 0.f);
    ed[(size_t)r * 128 + lane + 64] = fmaxf((e1 - mean) * rs * ee_g[lane + 64] + ee_bt[lane + 64], 0.f);
}

// ---------------------------------------------------------------------------
// Per-layer node precompute (fp32):
//   cI[p][t] = b1[t] + sum_k nd[p][k] * W1[(128+k)][t]
// also ndb[p][*] = bf16(nd[p][*]).   one block per node p, 512 threads.
// ---------------------------------------------------------------------------
__global__ __launch_bounds__(512) void k_pre(
    const float* __restrict__ nd, const float* __restrict__ W1,
    const float* __restrict__ b1,
    float* __restrict__ cI, ushort_t* __restrict__ ndb) {
    __shared__ float ndl[128];
    int p = blockIdx.x, t = threadIdx.x;
    if (t < 128) {
        float v = nd[(size_t)p * 128 + t];
        ndl[t] = v;
        ndb[(size_t)p * 128 + t] = f2b(v);
    }
    __syncthreads();
    const float* wm = W1 + (size_t)128 * 512 + t;
    float a1 = b1[t];
    #pragma unroll 4
    for (int k = 0; k < 128; ++k) a1 += ndl[k] * wm[(size_t)k * 512];
    cI[(size_t)p * 512 + t] = a1;
}

// ---------------------------------------------------------------------------
// msgs[r] = adj[r] * dot(ed[r][:], nd[i][:])   one wave per row
// ---------------------------------------------------------------------------
__global__ void k_msgs(const float* __restrict__ ed, const float* __restrict__ nd,
                       const float* __restrict__ adjf, float* __restrict__ msgs) {
    int r = blockIdx.x * 4 + (threadIdx.x >> 6);
    int lane = threadIdx.x & 63;
    int i = r >> 8;
    const float* er = ed + (size_t)r * 128;
    const float* nr = nd + (size_t)i * 128;
    float sum = er[lane] * nr[lane] + er[lane + 64] * nr[lane + 64];
    #pragma unroll
    for (int off = 1; off < 64; off <<= 1) sum += __shfl_xor(sum, off, 64);
    if (lane == 0) msgs[r] = adjf[r] * sum;
}

// ---------------------------------------------------------------------------
// Generic fp32 row-MLP: out = [res +] relu(LN(concat(in0,in1) @ W1 + b1)) @ W2 + b2
// one block (512 threads) per row; K = w0 + w1n <= 384; O <= 128
// ---------------------------------------------------------------------------
__global__ __launch_bounds__(512) void k_mlp(
    const float* __restrict__ in0, int w0, const float* __restrict__ in1, int w1n,
    const float* __restrict__ W1, const float* __restrict__ b1,
    const float* __restrict__ g, const float* __restrict__ bt,
    const float* __restrict__ W2, const float* __restrict__ b2, int O,
    const float* __restrict__ res, float* __restrict__ out) {
    __shared__ float ni[384];
    __shared__ float hsh[512];
    __shared__ float part[4][128];
    __shared__ float red[16];
    int row = blockIdx.x;
    int t = threadIdx.x;
    int K = w0 + w1n;
    if (t < w0) ni[t] = in0[(size_t)row * w0 + t];
    else if (t < K) ni[t] = in1[(size_t)row * w1n + (t - w0)];
    __syncthreads();
    float acc = b1[t];
    #pragma unroll 4
    for (int k = 0; k < K; ++k) acc += ni[k] * W1[(size_t)k * 512 + t];
    float s = acc, q = acc * acc;
    #pragma unroll
    for (int off = 1; off < 64; off <<= 1) {
        s += __shfl_xor(s, off, 64);
        q += __shfl_xor(q, off, 64);
    }
    int wv = t >> 6;
    if ((t & 63) == 0) { red[wv] = s; red[8 + wv] = q; }
    __syncthreads();
    float S = 0.f, Q = 0.f;
    #pragma unroll
    for (int w = 0; w < 8; ++w) { S += red[w]; Q += red[8 + w]; }
    float mean = S * (1.f / 512.f);
    float var = Q * (1.f / 512.f) - mean * mean;
    float rs = rsqrtf(var + LNEPS);
    hsh[t] = fmaxf((acc - mean) * rs * g[t] + bt[t], 0.f);
    __syncthreads();
    int qd = t >> 7, c = t & 127;
    float pacc = 0.f;
    if (c < O) {
        #pragma unroll 4
        for (int kk = 0; kk < 128; ++kk)
            pacc += hsh[qd * 128 + kk] * W2[(size_t)(qd * 128 + kk) * O + c];
    }
    part[qd][c] = pacc;
    __syncthreads();
    if (t < O) {
        float v = part[0][t] + part[1][t] + part[2][t] + part[3][t] + b2[t];
        if (res) v += res[(size_t)row * O + t];
        out[(size_t)row * O + t] = v;
    }
}

// ---------------------------------------------------------------------------
// Fused edge update (in-place on ed), bf16 MFMA, K=256 (nd_i hoisted to cI).
// Block: 512 threads (8 waves), 64 edge rows; i fixed, j = jbase + row.
//   h_pre = [ed_row | nd_j] @ W1' (MFMA) + cI[i]  -> LN -> relu
//   out   = h @ W2 + b2 + ed_row  (in-place)
// GEMM1: wave w -> 64 hidden cols (acc[4][4] = 64 regs, no spill at 128 budget)
// GEMM2: wave w -> row-tile (w>>1), col-half (w&1)*64 (acc2[4] = 16 regs)
// LDS 68.5KB: ei stage [64][256]bf16 (32KB, low half) then h [64][512]bf16 (64KB)
//             red [8][64][2] f32 @65536, stats [64][2] f32 @69632
// 2 blocks/CU, 16 waves/CU.
// ---------------------------------------------------------------------------
__global__ __launch_bounds__(512, 4) void k_edge(
    float* ed, const ushort_t* __restrict__ ndb, const float* __restrict__ cIg,
    const ushort_t* __restrict__ w1P,
    const float* __restrict__ g, const float* __restrict__ bt,
    const ushort_t* __restrict__ w2P, const float* __restrict__ b2) {
    __shared__ char smem[70144];
    const int tid = threadIdx.x;
    const int w = tid >> 6, lane = tid & 63;
    const int l15 = lane & 15, lhi = lane >> 4;
    const int rbase = blockIdx.x * 64;
    const int ib = rbase >> 8;          // fixed node i for this block
    const int jbase = rbase & 255;

    // ---- stage ei = [ed bf16 | ndb] : 64 rows x 32 chunks(16B), XOR-swz by row&7
    #pragma unroll
    for (int it = 0; it < 4; ++it) {
        int c = tid + it * 512;
        int row = c >> 5, q = c & 31;
        uint4 pk;
        if (q < 16) {
            const float4* sp = (const float4*)(ed + (size_t)(rbase + row) * 128 + q * 8);
            float4 v0 = sp[0], v1 = sp[1];
            pk.x = (unsigned)f2b(v0.x) | ((unsigned)f2b(v0.y) << 16);
            pk.y = (unsigned)f2b(v0.z) | ((unsigned)f2b(v0.w) << 16);
            pk.z = (unsigned)f2b(v1.x) | ((unsigned)f2b(v1.y) << 16);
            pk.w = (unsigned)f2b(v1.z) | ((unsigned)f2b(v1.w) << 16);
        } else {
            pk = *(const uint4*)(ndb + (size_t)(jbase + row) * 128 + (q - 16) * 8);
        }
        *(uint4*)(smem + row * 512 + ((q ^ (row & 7)) * 16)) = pk;
    }
    __syncthreads();

    // ---- GEMM1: wave w -> hidden cols [w*64, w*64+64), K=256 (8 kb)
    f32x4 acc[4][4];
    f32x4 zero = {0.f, 0.f, 0.f, 0.f};
    #pragma unroll
    for (int m = 0; m < 4; ++m)
        #pragma unroll
        for (int n = 0; n < 4; ++n) acc[m][n] = zero;

    const int cw = w * 64;
    #pragma unroll 2
    for (int kb = 0; kb < 8; ++kb) {
        short8 a[4];
        #pragma unroll
        for (int m = 0; m < 4; ++m) {
            int row = m * 16 + l15;
            a[m] = *(const short8*)(smem + row * 512 + (((kb * 4 + lhi) ^ (row & 7)) * 16));
        }
        #pragma unroll
        for (int n = 0; n < 4; ++n) {
            short8 b = *(const short8*)(w1P + ((((w * 4 + n) * 8 + kb) << 6) + lane) * 8);
            #pragma unroll
            for (int m = 0; m < 4; ++m)
                acc[m][n] = __builtin_amdgcn_mfma_f32_16x16x32_bf16(a[m], b, acc[m][n], 0, 0, 0);
        }
    }

    // ---- add cI (broadcast, i fixed), LN stats per row
    float* red = (float*)(smem + 65536);     // [8][64][2]
    float* stats = (float*)(smem + 69632);   // [64][2]
    {
        float ci[4];
        #pragma unroll
        for (int n = 0; n < 4; ++n) ci[n] = cIg[(size_t)ib * 512 + cw + n * 16 + l15];
        #pragma unroll
        for (int m = 0; m < 4; ++m) {
            float s[4] = {0.f, 0.f, 0.f, 0.f}, q[4] = {0.f, 0.f, 0.f, 0.f};
            #pragma unroll
            for (int n = 0; n < 4; ++n)
                #pragma unroll
                for (int e = 0; e < 4; ++e) {
                    float v = acc[m][n][e] + ci[n];
                    acc[m][n][e] = v;
                    s[e] += v; q[e] += v * v;
                }
            #pragma unroll
            for (int off = 1; off < 16; off <<= 1)
                #pragma unroll
                for (int e = 0; e < 4; ++e) {
                    s[e] += __shfl_xor(s[e], off, 64);
                    q[e] += __shfl_xor(q[e], off, 64);
                }
            if (l15 == 0) {
                #pragma unroll
                for (int e = 0; e < 4; ++e) {
                    int row = m * 16 + lhi * 4 + e;
                    red[(w * 64 + row) * 2 + 0] = s[e];
                    red[(w * 64 + row) * 2 + 1] = q[e];
                }
            }
        }
    }
    __syncthreads();
    if (tid < 64) {
        float S = 0.f, Q = 0.f;
        #pragma unroll
        for (int ww = 0; ww < 8; ++ww) {
            S += red[(ww * 64 + tid) * 2 + 0];
            Q += red[(ww * 64 + tid) * 2 + 1];
        }
        float mean = S * (1.f / 512.f);
        float var = Q * (1.f / 512.f) - mean * mean;
        stats[tid * 2 + 0] = mean;
        stats[tid * 2 + 1] = rsqrtf(var + LNEPS);
    }
    __syncthreads();

    // ---- LN apply + relu, write h [64][512] bf16 XOR-swz (overwrites ei region)
    {
        float gg[4], bb[4];
        #pragma unroll
        for (int n = 0; n < 4; ++n) {
            gg[n] = g[cw + n * 16 + l15];
            bb[n] = bt[cw + n * 16 + l15];
        }
        #pragma unroll
        for (int m = 0; m < 4; ++m)
            #pragma unroll
            for (int e = 0; e < 4; ++e) {
                int row = m * 16 + lhi * 4 + e;
                float mean = stats[row * 2 + 0];
                float rs = stats[row * 2 + 1];
                #pragma unroll
                for (int n = 0; n < 4; ++n) {
                    float v = fmaxf((acc[m][n][e] - mean) * rs * gg[n] + bb[n], 0.f);
                    int p = cw + n * 16 + l15;
                    int addr = row * 1024 + (((p >> 3) ^ (row & 7)) * 16) + (p & 7) * 2;
                    *(ushort_t*)(smem + addr) = f2b(v);
                }
            }
    }
    __syncthreads();

    // ---- GEMM2: wave w -> rows (w>>1)*16..+15, cols (w&1)*64..+63; K=512
    const int rt = w >> 1, ch2 = w & 1;
    f32x4 acc2[4];
    #pragma unroll
    for (int n2 = 0; n2 < 4; ++n2) acc2[n2] = zero;
    const int arow = rt * 16 + l15;
    #pragma unroll 2
    for (int kbg = 0; kbg < 16; ++kbg) {
        short8 a = *(const short8*)(smem + arow * 1024 + (((kbg * 4 + lhi) ^ (arow & 7)) * 16));
        #pragma unroll
        for (int n2 = 0; n2 < 4; ++n2) {
            int c2g = ch2 * 4 + n2;
            short8 b = *(const short8*)(w2P + (((c2g * 16 + kbg) << 6) + lane) * 8);
            acc2[n2] = __builtin_amdgcn_mfma_f32_16x16x32_bf16(a, b, acc2[n2], 0, 0, 0);
        }
    }

    // ---- epilogue: residual + bias
    #pragma unroll
    for (int n2 = 0; n2 < 4; ++n2) {
        int col = ch2 * 64 + n2 * 16 + l15;
        float bc = b2[col];
        #pragma unroll
        for (int e = 0; e < 4; ++e) {
            int row = rt * 16 + lhi * 4 + e;
            size_t off = (size_t)(rbase + row) * 128 + col;
            ed[off] = acc2[n2][e] + bc + ed[off];
        }
    }
}

// ---------------------------------------------------------------------------
extern "C" void kernel_launch(void* const* d_in, const int* in_sizes, int n_in,
                              void* d_out, int out_size, void* d_ws, size_t ws_size,
                              hipStream_t stream) {
    const float* nodes  = (const float*)d_in[0];
    const float* coords = (const float*)d_in[1];
    const float* ee_w   = (const float*)d_in[2];
    const float* ee_b   = (const float*)d_in[3];
    const float* ee_g   = (const float*)d_in[4];
    const float* ee_bt  = (const float*)d_in[5];
    const float* nu1_w  = (const float*)d_in[6];
    const float* nu1_b  = (const float*)d_in[7];
    const float* nu_g   = (const float*)d_in[8];
    const float* nu_bt  = (const float*)d_in[9];
    const float* nu2_w  = (const float*)d_in[10];
    const float* nu2_b  = (const float*)d_in[11];
    const float* eu1_w  = (const float*)d_in[12];
    const float* eu1_b  = (const float*)d_in[13];
    const float* eu_g   = (const float*)d_in[14];
    const float* eu_bt  = (const float*)d_in[15];
    const float* eu2_w  = (const float*)d_in[16];
    const float* eu2_b  = (const float*)d_in[17];
    const float* sp1_w  = (const float*)d_in[18];
    const float* sp1_b  = (const float*)d_in[19];
    const float* sp_g   = (const float*)d_in[20];
    const float* sp_bt  = (const float*)d_in[21];
    const float* sp2_w  = (const float*)d_in[22];
    const float* sp2_b  = (const float*)d_in[23];
    const float* no1_w  = (const float*)d_in[24];
    const float* no1_b  = (const float*)d_in[25];
    const float* no_g   = (const float*)d_in[26];
    const float* no_bt  = (const float*)d_in[27];
    const float* no2_w  = (const float*)d_in[28];
    const float* no2_b  = (const float*)d_in[29];

    char* p = (char*)d_ws;
    float* ed      = (float*)p;     p += (size_t)65536 * 128 * 4;   // 33.5 MB
    float* ndA     = (float*)p;     p += 256 * 128 * 4;
    float* ndB     = (float*)p;     p += 256 * 128 * 4;
    ushort_t* ndb  = (ushort_t*)p;  p += 256 * 128 * 2;
    float* msgs    = (float*)p;     p += 65536 * 4;
    float* adjf    = (float*)p;     p += 65536 * 4;
    float* cI      = (float*)p;     p += 256 * 512 * 4;
    ushort_t* w1P  = (ushort_t*)p;  p += (size_t)4 * 131072 * 2;    // 1 MB
    ushort_t* w2P  = (ushort_t*)p;  p += (size_t)4 * 65536 * 2;     // 512 KB

    k_convw<<<256, 256, 0, stream>>>(eu1_w, eu2_w, w1P, w2P);
    k_init<<<16384, 256, 0, stream>>>(coords, ee_w, ee_b, ee_g, ee_bt, ed, adjf);

    const float* nd_cur = nodes;
    float* nd_bufs[2] = {ndA, ndB};
    for (int l = 0; l < 4; ++l) {
        float* nd_next = nd_bufs[l & 1];
        k_pre<<<256, 512, 0, stream>>>(nd_cur, eu1_w + (size_t)l * 384 * 512,
                                       eu1_b + l * 512, cI, ndb);
        k_msgs<<<16384, 256, 0, stream>>>(ed, nd_cur, adjf, msgs);
        k_mlp<<<256, 512, 0, stream>>>(nd_cur, 128, msgs, 256,
            nu1_w + (size_t)l * 384 * 512, nu1_b + l * 512, nu_g + l * 512, nu_bt + l * 512,
            nu2_w + (size_t)l * 512 * 128, nu2_b + l * 128, 128, nd_cur, nd_next);
        k_edge<<<1024, 512, 0, stream>>>(ed, ndb, cI,
            w1P + (size_t)l * 131072, eu_g + l * 512, eu_bt + l * 512,
            w2P + (size_t)l * 65536, eu2_b + l * 128);
        nd_cur = nd_next;
    }

    float* out_nodes  = (float*)d_out;
    float* out_coords = out_nodes + 32768;
    k_mlp<<<256, 512, 0, stream>>>(nd_cur, 128, nullptr, 0,
        no1_w, no1_b, no_g, no_bt, no2_w, no2_b, 128, nullptr, out_nodes);
    k_mlp<<<256, 512, 0, stream>>>(out_nodes, 128, nullptr, 0,
        sp1_w, sp1_b, sp_g, sp_bt, sp2_w, sp2_b, 3, nullptr, out_coords);
}